// Round 25
// baseline (118.974 us; speedup 1.0000x reference)
//
#include <hip/hip_runtime.h>

// MultiHeadAttention: x@Wq/Wk/Wv -> causal flash attn -> @Wo
// B=2 S=2048 H=16 D=64 HIDDEN=1024. All MFMA bf16 16x16x32, f32 accum.
//
// R24 = R23 (anchor: 109.0us) with gemm_qkv double-buffered, ONE barrier per
// K-step: stage kt+1 into buf^1 (6 fire-and-forget gloads) BEFORE computing
// buf, then a single __syncthreads whose vmcnt drain overlaps the load
// latency with the ~500cyc compute phase (was: issue -> immediate barrier ->
// full latency exposed, twice-barriered). Legal now because staging is
// all-gload (R12's dbuf failure was reg-staged f32 held across compute).
// LDS 24->48KB = 3 blocks/CU by LDS == grid residency (no occupancy loss).
//
// Workspace map (64 MiB), with region reuse:
//   [0)         PO bf16 partial O: 1280 slices x 128 rows x 64 d (21 MiB)
//   [25165824)  ML f32: 1280 slices x 128 rows x {m,l}  (1.31 MiB)
//   [31457280)  woT (live until gemm_out)   [wT block: 25165824 + z*2MiB]
//   [33554432)  Qb  bf16 [4096][1024]  (pre-scaled by 0.125*log2(e))
//   [41943040)  Kb  bf16 [4096][1024]
//   [50331648)  VTb bf16 [b][h][d][s] = [2][16][64][2048]
//   [58720256)  Ob  bf16 [4096][1024]
//   NOTE: ML aliases wqT/wkT which are DEAD after gemm_qkv completes.

using u16 = unsigned short;
typedef __bf16 bf16x8 __attribute__((ext_vector_type(8)));
typedef short  s16x8  __attribute__((ext_vector_type(8)));
typedef float  f32x4  __attribute__((ext_vector_type(4)));

#define SEQ   2048
#define QSC   0.18033688f   /* 0.125 * log2(e) */

__device__ __forceinline__ u16 to_bf16(float f) {
  return __builtin_bit_cast(u16, (__bf16)f);
}
__device__ __forceinline__ float from_bf16(u16 v) {
  return __builtin_bit_cast(float, ((unsigned)v) << 16);
}
__device__ __forceinline__ bf16x8 frag_cast(s16x8 v) {
  return __builtin_bit_cast(bf16x8, v);
}
__device__ __forceinline__ f32x4 mfma16(bf16x8 a, bf16x8 b, f32x4 c) {
  return __builtin_amdgcn_mfma_f32_16x16x32_bf16(a, b, c, 0, 0, 0);
}
__device__ __forceinline__ void gload_lds16(const void* g, void* l) {
  __builtin_amdgcn_global_load_lds(
      (const __attribute__((address_space(1))) void*)g,
      (__attribute__((address_space(3))) void*)l, 16, 0, 0);
}

// ---------------- weight transpose+convert: w[K][N] f32 -> wT[N][K] bf16 --
__global__ __launch_bounds__(256) void transpose_w(const float* __restrict__ wq,
                                                   const float* __restrict__ wk,
                                                   const float* __restrict__ wv,
                                                   const float* __restrict__ wo,
                                                   u16* __restrict__ wT) {
  __shared__ float tile[32][33];
  const float* src = blockIdx.z == 0 ? wq : blockIdx.z == 1 ? wk
                     : blockIdx.z == 2 ? wv : wo;
  u16* dst = wT + (size_t)blockIdx.z * 1048576;
  const int x0 = blockIdx.x * 32, y0 = blockIdx.y * 32;
  const int tx = threadIdx.x, ty = threadIdx.y;  // block (32,8)
#pragma unroll
  for (int i = 0; i < 4; ++i)
    tile[ty + i * 8][tx] = src[(size_t)(y0 + ty + i * 8) * 1024 + x0 + tx];
  __syncthreads();
#pragma unroll
  for (int i = 0; i < 4; ++i)
    dst[(size_t)(x0 + ty + i * 8) * 1024 + y0 + tx] = to_bf16(tile[tx][ty + i * 8]);
}

// ---------------- fused QKV GEMM, all-gload dbuf, cvt at frag-read --------
// z=0: Qb = q@wqT^T (scaled); z=1: Kb = k@wkT^T; z=2 swapped: VT = wvT@v^T.
// Flat 768-block grid, XCD-swizzled: f = bx%8 + 8*(by + 8*(bx/8 + 4*z)).
// Per-buffer layout: [0,16K) f32 tile [128 rows][128B] (row-XOR via
// pre-swizzled global src), [16K,24K) bf16 weight tile (ksrc/fsw swizzle).
// Stage kt+1 -> buf^1 before computing buf; ONE barrier per step.
__global__ __launch_bounds__(256) void gemm_qkv(const float* __restrict__ Xq,
                                                const float* __restrict__ Xk,
                                                const float* __restrict__ Xv,
                                                const u16* __restrict__ WT,
                                                u16* __restrict__ Qb,
                                                u16* __restrict__ Kb,
                                                u16* __restrict__ VTb) {
  __shared__ __align__(16) char lds[49152];   // 2 x (16KB f32 + 8KB weight)

  // decode XCD-swizzled flat id
  const int f = blockIdx.x;
  const int bxm = f & 7, r1 = f >> 3;
  const int by = r1 & 7, r2 = r1 >> 3;
  const int bxd = r2 & 3, z = r2 >> 2;
  const int bx = bxm + 8 * bxd;            // 0..31

  const u16* Gbf;      // bf16 operand (gload_lds, bf16 tile)
  const float* Gf32;   // f32 operand (gload_lds raw, f32 tile)
  int row0, n0;
  if (z == 2) {
    Gbf = WT + 2097152;             // A = wvT [1024][1024]
    Gf32 = Xv;                      // B = value rows (seq)
    row0 = by * 128;                // 8 row-blocks over 1024
    n0 = bx * 128;                  // 32 col-blocks over 4096
  } else {
    Gf32 = z ? Xk : Xq;             // A = x rows (seq)
    Gbf = WT + (size_t)z * 1048576; // B = wT
    row0 = bx * 128;                // 32 row-blocks over 4096
    n0 = by * 128;                  // 8 col-blocks over 1024
  }
  const int frow0 = (z == 2) ? n0 : row0;   // f32 operand tile base row
  const int wrow0 = (z == 2) ? row0 : n0;   // weight operand tile base row

  const int tid = threadIdx.x;
  const int w = tid >> 6, lane = tid & 63;
  const int g = lane >> 4, c = lane & 15;
  const int wr = w >> 1, wc = w & 1;

  f32x4 acc[4][4];
#pragma unroll
  for (int i = 0; i < 4; ++i)
#pragma unroll
    for (int j = 0; j < 4; ++j) acc[i][j] = (f32x4){0.f, 0.f, 0.f, 0.f};

  const int sub = lane >> 2;                       // row within 16-row chunk
  const int kq = lane & 3;                         // k-group slot
  const int ksrc = (kq ^ ((sub >> 1) & 3)) * 8;    // swizzled source k-group
  const int fsw = ((c >> 1) & 3);                  // frag-read swizzle key

  // f32 staging: lane's dest slot is (row = j*32 + w*8 + lane>>3, unit = lane&7);
  // source col-group pre-swizzled so LDS holds unit u = cg ^ (row&7).
  const int fsrow = w * 8 + (lane >> 3);           // row within 32-row segment
  const int fscg = ((lane & 7) ^ (lane >> 3)) * 4; // source col-group elems

#define STAGE(KT, B)                                                                           \
  {                                                                                            \
    const int k0_ = (KT)*32;                                                                   \
    char* fb_ = lds + (B)*24576;                                                               \
    _Pragma("unroll") for (int j = 0; j < 4; ++j)                                              \
        gload_lds16(Gf32 + (size_t)(frow0 + j * 32 + fsrow) * 1024 + k0_ + fscg,               \
                    fb_ + j * 4096 + w * 1024);                                                \
    _Pragma("unroll") for (int it = 0; it < 2; ++it) {                                         \
      const int ch_ = w * 2 + it;                                                              \
      gload_lds16(Gbf + (size_t)(wrow0 + ch_ * 16 + sub) * 1024 + k0_ + ksrc,                  \
                  fb_ + 16384 + ch_ * 1024);                                                   \
    }                                                                                          \
  }

  STAGE(0, 0);
  __syncthreads();

  int cur = 0;
  for (int kt = 0; kt < 32; ++kt) {
    if (kt + 1 < 32) STAGE(kt + 1, cur ^ 1);   // fire-and-forget into buf^1

    const char* f32t = lds + cur * 24576;
    const char* wtile = f32t + 16384;

    bf16x8 af[4], bfr[4];
    if (z != 2) {
      // A from f32 tile (cvt), B from bf16 weight tile
#pragma unroll
      for (int mi = 0; mi < 4; ++mi) {
        const int rr = wr * 64 + mi * 16 + c;
        const int rs = rr & 7;
        const f32x4 lo = *(const f32x4*)(f32t + rr * 128 + (((2 * g) ^ rs) << 4));
        const f32x4 hi = *(const f32x4*)(f32t + rr * 128 + (((2 * g + 1) ^ rs) << 4));
        s16x8 o;
        o[0] = (short)to_bf16(lo[0]); o[1] = (short)to_bf16(lo[1]);
        o[2] = (short)to_bf16(lo[2]); o[3] = (short)to_bf16(lo[3]);
        o[4] = (short)to_bf16(hi[0]); o[5] = (short)to_bf16(hi[1]);
        o[6] = (short)to_bf16(hi[2]); o[7] = (short)to_bf16(hi[3]);
        af[mi] = frag_cast(o);
      }
#pragma unroll
      for (int ni = 0; ni < 4; ++ni)
        bfr[ni] = frag_cast(*(const s16x8*)(wtile + (wc * 64 + ni * 16 + c) * 64 + ((g ^ fsw) << 4)));
    } else {
      // A from bf16 weight tile, B from f32 tile (cvt)
#pragma unroll
      for (int mi = 0; mi < 4; ++mi)
        af[mi] = frag_cast(*(const s16x8*)(wtile + (wr * 64 + mi * 16 + c) * 64 + ((g ^ fsw) << 4)));
#pragma unroll
      for (int ni = 0; ni < 4; ++ni) {
        const int rr = wc * 64 + ni * 16 + c;
        const int rs = rr & 7;
        const f32x4 lo = *(const f32x4*)(f32t + rr * 128 + (((2 * g) ^ rs) << 4));
        const f32x4 hi = *(const f32x4*)(f32t + rr * 128 + (((2 * g + 1) ^ rs) << 4));
        s16x8 o;
        o[0] = (short)to_bf16(lo[0]); o[1] = (short)to_bf16(lo[1]);
        o[2] = (short)to_bf16(lo[2]); o[3] = (short)to_bf16(lo[3]);
        o[4] = (short)to_bf16(hi[0]); o[5] = (short)to_bf16(hi[1]);
        o[6] = (short)to_bf16(hi[2]); o[7] = (short)to_bf16(hi[3]);
        bfr[ni] = frag_cast(o);
      }
    }
#pragma unroll
    for (int mi = 0; mi < 4; ++mi)
#pragma unroll
      for (int ni = 0; ni < 4; ++ni)
        acc[mi][ni] = mfma16(af[mi], bfr[ni], acc[mi][ni]);

    __syncthreads();    // drains kt+1 loads (overlapped with compute above)
    cur ^= 1;
  }

  const float sc = (z == 0) ? QSC : 1.0f;
#pragma unroll
  for (int mi = 0; mi < 4; ++mi) {
    const int rowb = row0 + wr * 64 + mi * 16 + g * 4;
#pragma unroll
    for (int ni = 0; ni < 4; ++ni) {
      const int col = n0 + wc * 64 + ni * 16 + c;
#pragma unroll
      for (int r = 0; r < 4; ++r) {
        const int row = rowb + r;
        const float v = acc[mi][ni][r] * sc;
        if (z == 2) {
          // row = h*64+d, col = b*2048+s
          const int hh = row >> 6, d = row & 63;
          const int bb = col >> 11, s = col & 2047;
          VTb[((size_t)((bb * 16 + hh) * 64 + d)) * 2048 + s] = to_bf16(v);
        } else {
          u16* C = z == 0 ? Qb : Kb;
          C[(size_t)row * 1024 + col] = to_bf16(v);
        }
      }
    }
  }
}

// ---------------- out projection GEMM: BM=64, BN=128, f32 out ------------
// Flat 512-block grid, XCD-swizzled: f = bx%8 + 8*(by + 8*(bx/8)).
__global__ __launch_bounds__(256) void gemm_out(const u16* __restrict__ A,
                                                const u16* __restrict__ BT,
                                                float* __restrict__ C) {
  __shared__ u16 As[64 * 32];
  __shared__ u16 Bs[128 * 32];
  const int f = blockIdx.x;
  const int bxm = f & 7, r1 = f >> 3;
  const int by = r1 & 7, bxd = r1 >> 3;    // bxd 0..7
  const int bx = bxm + 8 * bxd;            // 0..63
  const int row0 = bx * 64;
  const int n0 = by * 128;

  const int tid = threadIdx.x;
  const int w = tid >> 6, lane = tid & 63;
  const int g = lane >> 4, c = lane & 15;
  const int wr = w >> 1, wc = w & 1;

  f32x4 acc[2][4];
#pragma unroll
  for (int i = 0; i < 2; ++i)
#pragma unroll
    for (int j = 0; j < 4; ++j) acc[i][j] = (f32x4){0.f, 0.f, 0.f, 0.f};

  const int sub = lane >> 2;
  const int kq = lane & 3;
  const int ksrc = (kq ^ ((sub >> 1) & 3)) * 8;
  const int fsw = ((c >> 1) & 3);

  for (int kt = 0; kt < 32; ++kt) {
    const int k0 = kt * 32;
    {
      const int row = w * 16 + sub;
      gload_lds16(A + (size_t)(row0 + row) * 1024 + k0 + ksrc, (char*)As + w * 1024);
    }
#pragma unroll
    for (int it = 0; it < 2; ++it) {
      const int ch = w * 2 + it;
      const int row = ch * 16 + sub;
      gload_lds16(BT + (size_t)(n0 + row) * 1024 + k0 + ksrc, (char*)Bs + ch * 1024);
    }
    __syncthreads();

    bf16x8 af[2], bfr[4];
#pragma unroll
    for (int mi = 0; mi < 2; ++mi)
      af[mi] = frag_cast(*(const s16x8*)((const char*)As + (wr * 32 + mi * 16 + c) * 64 + ((g ^ fsw) << 4)));
#pragma unroll
    for (int ni = 0; ni < 4; ++ni)
      bfr[ni] = frag_cast(*(const s16x8*)((const char*)Bs + (wc * 64 + ni * 16 + c) * 64 + ((g ^ fsw) << 4)));
#pragma unroll
    for (int mi = 0; mi < 2; ++mi)
#pragma unroll
      for (int ni = 0; ni < 4; ++ni)
        acc[mi][ni] = mfma16(af[mi], bfr[ni], acc[mi][ni]);
    __syncthreads();
  }

#pragma unroll
  for (int mi = 0; mi < 2; ++mi) {
    const int rowb = row0 + wr * 32 + mi * 16 + g * 4;
#pragma unroll
    for (int ni = 0; ni < 4; ++ni) {
      const int col = n0 + wc * 64 + ni * 16 + c;
#pragma unroll
      for (int r = 0; r < 4; ++r)
        C[(size_t)(rowb + r) * 1024 + col] = acc[mi][ni][r];
    }
  }
}

// ---------------- causal flash attention, 8-wave, KVBLK=128 ---------------
// (R8 dbuf version verbatim — measured 39.3us.) grid (40, 32) remapped
// XCD-wise. Slice covers <=4 kv tile-pairs (ns=(x+4)>>2; 40 slices/bh).
// 8 waves x 16 q-rows. Permuted-K LDS slot (kv&0x63)|((kv&4)<<2)|((kv&0x18)>>1);
// QK^T C-slot (kvf,g,r) holds kv=32(kvf>>1)+4(kvf&1)+8g+r -> PV A-frags
// packed in place. l via ones-MFMA. Writes bf16 partial O + f32 (m,l).
__global__ __launch_bounds__(512, 4) void attn_fwd(const u16* __restrict__ Qb,
                                                   const u16* __restrict__ Kb,
                                                   const u16* __restrict__ VTb,
                                                   u16* __restrict__ PO,
                                                   float* __restrict__ ML) {
  __shared__ u16 Ks[2][128 * 64];   // [buf][slot][d] swizzled   (32 KB)
  __shared__ u16 VTs[2][64 * 128];  // [buf][d][kv] swizzled     (32 KB)

  const int tid = threadIdx.x;
  const int w = tid >> 6, lane = tid & 63;
  const int g = lane >> 4, c = lane & 15;

  // XCD-aware remap: flat -> logical so each XCD gets 4 consecutive bh
  const int flat = blockIdx.x + 40 * blockIdx.y;
  const int logical = (flat & 7) * 160 + (flat >> 3);
  const int slice_id = logical % 40;
  const int bh = logical / 40;
  const int b = bh >> 4, h = bh & 15;

  // decode slice id -> (q-block x, slice sid); ns(x) = (x+4)>>2 over pairs
  int sid = slice_id, x = 0;
  for (; x < 16; ++x) {
    const int ns_ = (x + 4) >> 2;
    if (sid < ns_) break;
    sid -= ns_;
  }
  const int ns = (x + 4) >> 2;
  const int np = x + 1;                       // kv tile-pairs for q-block x
  const int t0 = (sid * np) / ns, t1 = ((sid + 1) * np) / ns;
  const int sg = slice_id + 40 * bh;          // global slice id
  const int q0w = x * 128 + w * 16;           // this wave's first q row

  // Q fragments (B-operand: n=q, k=d) in registers
  bf16x8 qfr[2];
#pragma unroll
  for (int ch = 0; ch < 2; ++ch)
    qfr[ch] = frag_cast(*(const s16x8*)(Qb + (size_t)(b * SEQ + q0w + c) * 1024 + h * 64 + ch * 32 + g * 8));

  s16x8 ones_s;
#pragma unroll
  for (int j = 0; j < 8; ++j) ones_s[j] = (short)0x3F80;  // bf16 1.0
  const bf16x8 onesf = frag_cast(ones_s);

  f32x4 oacc[4];
#pragma unroll
  for (int j = 0; j < 4; ++j) oacc[j] = (f32x4){0.f, 0.f, 0.f, 0.f};
  f32x4 lacc = (f32x4){0.f, 0.f, 0.f, 0.f};
  float m_run = -1e30f;

  // staging geometry
  const int srow = tid >> 3;        // K: 0..63 (+64 on 2nd pass)
  const int scol = (tid & 7) * 8;   // K col elems
  const int vd = tid >> 4;          // V: 0..31 (+32 on 2nd pass)
  const int vcol = (tid & 15) * 8;  // V col elems (kv within pair)

  s16x8 kreg[2], vreg[2];
#define LOADKV(T)                                                                              \
  {                                                                                            \
    const int kv0_ = (T)*128;                                                                  \
    _Pragma("unroll") for (int it = 0; it < 2; ++it) {                                         \
      kreg[it] = *(const s16x8*)(Kb + (size_t)(b * SEQ + kv0_ + srow + it * 64) * 1024 +       \
                                 h * 64 + scol);                                               \
      vreg[it] = *(const s16x8*)(VTb + ((size_t)(bh * 64 + vd + it * 32)) * 2048 + kv0_ +      \
                                 vcol);                                                        \
    }                                                                                          \
  }
#define WRITEKV(BUF)                                                                           \
  {                                                                                            \
    _Pragma("unroll") for (int it = 0; it < 2; ++it) {                                         \
      const int rr_ = srow + it * 64;                                                          \
      const int pr_ = (rr_ & 0x63) | ((rr_ & 4) << 2) | ((rr_ & 0x18) >> 1);                   \
      *(s16x8*)((char*)Ks[BUF] + pr_ * 128 + ((scol * 2) ^ ((pr_ & 7) << 4))) = kreg[it];      \
      const int vr_ = vd + it * 32;                                                            \
      *(s16x8*)((char*)VTs[BUF] + vr_ * 256 + ((vcol * 2) ^ ((vr_ & 7) << 4))) = vreg[it];     \
    }                                                                                          \
  }

  LOADKV(t0);
  WRITEKV(0);
  __syncthreads();

  int cur = 0;
  for (int t = t0; t < t1; ++t) {
    const bool pre = (t + 1 < t1);
    if (pre) LOADKV(t + 1);          // issue early; lands during compute

    const int kv0 = t * 128;
    if (!(kv0 > q0w + 15)) {         // wave has live rows in this pair
      // ---- S^T = K * Q^T over 128 kv: 8 kvf frags
      f32x4 sa[8];
#pragma unroll
      for (int i = 0; i < 8; ++i) sa[i] = (f32x4){0.f, 0.f, 0.f, 0.f};
#pragma unroll
      for (int kvf = 0; kvf < 8; ++kvf) {
        const int kr = kvf * 16 + c;
        const int rb = kr * 128, swz = (kr & 7) << 4;
#pragma unroll
        for (int ch = 0; ch < 2; ++ch) {
          const bf16x8 ak = frag_cast(*(const s16x8*)((char*)Ks[cur] + rb + ((ch * 64 + g * 16) ^ swz)));
          sa[kvf] = mfma16(ak, qfr[ch], sa[kvf]);
        }
      }

      // ---- mask (diagonal pairs only) + tile max
      float mt = -1e30f;
      if (kv0 + 127 > q0w) {         // diagonal pair: mask with permuted kv
        const int q_abs = q0w + c;
#pragma unroll
        for (int kvf = 0; kvf < 8; ++kvf) {
          const int kvb = kv0 + (kvf >> 1) * 32 + (kvf & 1) * 4 + 8 * g;
#pragma unroll
          for (int r = 0; r < 4; ++r) {
            float s = sa[kvf][r];
            if (kvb + r > q_abs) s = -30000.f;
            sa[kvf][r] = s;
            mt = fmaxf(mt, s);
          }
        }
      } else {
#pragma unroll
        for (int kvf = 0; kvf < 8; ++kvf)
#pragma unroll
          for (int r = 0; r < 4; ++r) mt = fmaxf(mt, sa[kvf][r]);
      }
      mt = fmaxf(mt, __shfl_xor(mt, 16));
      mt = fmaxf(mt, __shfl_xor(mt, 32));

      if (__any(mt > m_run + 8.f)) {   // defer-max (T13)
        const float m_new = fmaxf(m_run, mt);
        const float alpha = __builtin_amdgcn_exp2f(m_run - m_new);
        m_run = m_new;
#pragma unroll
        for (int r = 0; r < 4; ++r) {
          const float ar = __shfl(alpha, g * 4 + r);
#pragma unroll
          for (int df = 0; df < 4; ++df) oacc[df][r] *= ar;
          lacc[r] *= ar;
        }
      }

      // ---- exp2 + pack in place into PV A-fragments (4 ch of 32 kv)
      s16x8 pk[4];
#pragma unroll
      for (int kvf = 0; kvf < 8; ++kvf)
#pragma unroll
        for (int r = 0; r < 4; ++r) {
          const float p = __builtin_amdgcn_exp2f(sa[kvf][r] - m_run);
          pk[kvf >> 1][(kvf & 1) * 4 + r] = (short)to_bf16(p);
        }

      // ---- O += P*V ; l += P*1 (row-sum via MFMA, no shfl)
#pragma unroll
      for (int ch = 0; ch < 4; ++ch) {
        const bf16x8 ap = frag_cast(pk[ch]);
#pragma unroll
        for (int df = 0; df < 4; ++df) {
          const int dr = df * 16 + c;
          const bf16x8 bv = frag_cast(*(const s16x8*)((char*)VTs[cur] + dr * 256 +
                                                      ((ch * 64 + g * 16) ^ ((dr & 7) << 4))));
          oacc[df] = mfma16(ap, bv, oacc[df]);
        }
        lacc = mfma16(ap, onesf, lacc);
      }
    }

    if (pre) WRITEKV(cur ^ 1);   // write next buffer (others still read cur)
    __syncthreads();
    cur ^= 1;
  }

  // epilogue: bf16 unnormalized partial O; f32 (m,l)
  const size_t pob = (size_t)sg * 8192;
#pragma unroll
  for (int r = 0; r < 4; ++r) {
    const int row = w * 16 + g * 4 + r;
#pragma unroll
    for (int df = 0; df < 4; ++df)
      PO[pob + row * 64 + df * 16 + c] = to_bf16(oacc[df][r]);
  }
  if (g == 0)
    ML[sg * 256 + (w * 16 + c) * 2 + 0] = m_run;     // m for q=c
  if (c == 0) {
#pragma unroll
    for (int r = 0; r < 4; ++r)
      ML[sg * 256 + (w * 16 + g * 4 + r) * 2 + 1] = lacc[r];  // l for q=4g+r
  }
}

// ---------------- merge split-kv partials -> bf16 Ob ----------------------
// grid (16, 32), 512 thr: x = q-block (128 rows), y = bh. row=tid/4, 16 cols.
__global__ __launch_bounds__(512) void attn_merge(const u16* __restrict__ PO,
                                                  const float* __restrict__ ML,
                                                  u16* __restrict__ Ob) {
  const int x = blockIdx.x, bh = blockIdx.y;
  const int b = bh >> 4, h = bh & 15;
  const int tid = threadIdx.x;
  const int row = tid >> 2, c0 = (tid & 3) << 4;

  int base = 0;
  for (int xp = 0; xp < x; ++xp) base += (xp + 4) >> 2;
  const int ns = (x + 4) >> 2;
  const int sg0 = base + 40 * bh;

  float m[4], l[4], a[4];
  float M = -3e38f;
  for (int i = 0; i < ns; ++i) {
    m[i] = ML[(sg0 + i) * 256 + row * 2 + 0];
    l[i] = ML[(sg0 + i) * 256 + row * 2 + 1];
    M = fmaxf(M, m[i]);
  }
  float denom = 0.f;
  for (int i = 0; i < ns; ++i) {
    a[i] = __builtin_amdgcn_exp2f(m[i] - M);
    denom += a[i] * l[i];
  }
  const float inv = 1.f / denom;

  float o[16];
#pragma unroll
  for (int j = 0; j < 16; ++j) o[j] = 0.f;
  for (int i = 0; i < ns; ++i) {
    const float s = a[i] * inv;
    const u16* p = PO + (size_t)(sg0 + i) * 8192 + row * 64 + c0;
    const s16x8 v0 = *(const s16x8*)p;
    const s16x8 v1 = *(const s16x8*)(p + 8);
#pragma unroll
    for (int j = 0; j < 8; ++j) {
      o[j] += s * from_bf16((u16)v0[j]);
      o[8 + j] += s * from_bf16((u16)v1[j]);
    }
  }

  s16x8 lo, hi;
#pragma unroll
  for (int j = 0; j < 8; ++j) {
    lo[j] = (short)to_bf16(o[j]);
    hi[j] = (short)to_bf16(o[8 + j]);
  }
  u16* dst = Ob + (size_t)(b * SEQ + x * 128 + row) * 1024 + h * 64 + c0;
  *(s16x8*)dst = lo;
  *(s16x8*)(dst + 8) = hi;
}

// --------------------------------------------------------------------------
extern "C" void kernel_launch(void* const* d_in, const int* in_sizes, int n_in,
                              void* d_out, int out_size, void* d_ws, size_t ws_size,
                              hipStream_t stream) {
  const float* query = (const float*)d_in[0];
  const float* key_ = (const float*)d_in[1];
  const float* value = (const float*)d_in[2];
  const float* w_q = (const float*)d_in[3];
  const float* w_k = (const float*)d_in[4];
  const float* w_v = (const float*)d_in[5];
  const float* w_o = (const float*)d_in[6];

  char* ws = (char*)d_ws;
  u16* PO = (u16*)(ws + 0);
  u16* wT = (u16*)(ws + 25165824);
  float* ML = (float*)(ws + 25165824);   // aliases wqT/wkT (dead post-qkv)
  u16* Qb = (u16*)(ws + 33554432);
  u16* Kb = (u16*)(ws + 41943040);
  u16* VTb = (u16*)(ws + 50331648);
  u16* Ob = (u16*)(ws + 58720256);

  transpose_w<<<dim3(32, 32, 4), dim3(32, 8), 0, stream>>>(w_q, w_k, w_v, w_o, wT);
  gemm_qkv<<<dim3(768), 256, 0, stream>>>(query, key_, value, wT, Qb, Kb, VTb);
  attn_fwd<<<dim3(40, 32), 512, 0, stream>>>(Qb, Kb, VTb, PO, ML);
  attn_merge<<<dim3(16, 32), 512, 0, stream>>>(PO, ML, Ob);
  gemm_out<<<dim3(512), 256, 0, stream>>>(Ob, wT + 3145728, (float*)d_out);
}

// Round 26
// 108.862 us; speedup vs baseline: 1.0929x; 1.0929x over previous
//
#include <hip/hip_runtime.h>

// MultiHeadAttention: x@Wq/Wk/Wv -> causal flash attn -> @Wo
// B=2 S=2048 H=16 D=64 HIDDEN=1024. All MFMA bf16 16x16x32, f32 accum.
//
// FINAL (R25) = R21/R23 verbatim — measured best 109.0us, reproduced twice.
// R24's single-barrier dbuf regressed (+10us): __syncthreads drains vmcnt(0)
// including the just-issued next-tile loads (guide m99/m131 mechanism), so
// the overlap is structurally zero without raw s_barrier + counted vmcnt.
// Configuration ledger:
//  - gemm_qkv: fused f32->bf16, BOTH operands via fire-and-forget
//    global_load_lds; f32 staged raw (row-XOR via pre-swizzled global src),
//    converted at frag-read in VALU slack. XCD-swizzled flat grid.
//  - attn: KVBLK=128 pairs, permuted-K LDS (P never crosses lanes),
//    l via ones-MFMA, balanced <=4-pair split-kv, dbuf, XCD remap.
//  - attn_merge + XCD-swizzled gemm_out epilogue.
//
// Workspace map (64 MiB), with region reuse:
//   [0)         PO bf16 partial O: 1280 slices x 128 rows x 64 d (21 MiB)
//   [25165824)  ML f32: 1280 slices x 128 rows x {m,l}  (1.31 MiB)
//   [31457280)  woT (live until gemm_out)   [wT block: 25165824 + z*2MiB]
//   [33554432)  Qb  bf16 [4096][1024]  (pre-scaled by 0.125*log2(e))
//   [41943040)  Kb  bf16 [4096][1024]
//   [50331648)  VTb bf16 [b][h][d][s] = [2][16][64][2048]
//   [58720256)  Ob  bf16 [4096][1024]
//   NOTE: ML aliases wqT/wkT which are DEAD after gemm_qkv completes.

using u16 = unsigned short;
typedef __bf16 bf16x8 __attribute__((ext_vector_type(8)));
typedef short  s16x8  __attribute__((ext_vector_type(8)));
typedef float  f32x4  __attribute__((ext_vector_type(4)));

#define SEQ   2048
#define QSC   0.18033688f   /* 0.125 * log2(e) */

__device__ __forceinline__ u16 to_bf16(float f) {
  return __builtin_bit_cast(u16, (__bf16)f);
}
__device__ __forceinline__ float from_bf16(u16 v) {
  return __builtin_bit_cast(float, ((unsigned)v) << 16);
}
__device__ __forceinline__ bf16x8 frag_cast(s16x8 v) {
  return __builtin_bit_cast(bf16x8, v);
}
__device__ __forceinline__ f32x4 mfma16(bf16x8 a, bf16x8 b, f32x4 c) {
  return __builtin_amdgcn_mfma_f32_16x16x32_bf16(a, b, c, 0, 0, 0);
}
__device__ __forceinline__ void gload_lds16(const void* g, void* l) {
  __builtin_amdgcn_global_load_lds(
      (const __attribute__((address_space(1))) void*)g,
      (__attribute__((address_space(3))) void*)l, 16, 0, 0);
}

// ---------------- weight transpose+convert: w[K][N] f32 -> wT[N][K] bf16 --
__global__ __launch_bounds__(256) void transpose_w(const float* __restrict__ wq,
                                                   const float* __restrict__ wk,
                                                   const float* __restrict__ wv,
                                                   const float* __restrict__ wo,
                                                   u16* __restrict__ wT) {
  __shared__ float tile[32][33];
  const float* src = blockIdx.z == 0 ? wq : blockIdx.z == 1 ? wk
                     : blockIdx.z == 2 ? wv : wo;
  u16* dst = wT + (size_t)blockIdx.z * 1048576;
  const int x0 = blockIdx.x * 32, y0 = blockIdx.y * 32;
  const int tx = threadIdx.x, ty = threadIdx.y;  // block (32,8)
#pragma unroll
  for (int i = 0; i < 4; ++i)
    tile[ty + i * 8][tx] = src[(size_t)(y0 + ty + i * 8) * 1024 + x0 + tx];
  __syncthreads();
#pragma unroll
  for (int i = 0; i < 4; ++i)
    dst[(size_t)(x0 + ty + i * 8) * 1024 + y0 + tx] = to_bf16(tile[tx][ty + i * 8]);
}

// ---------------- fused QKV GEMM, all-gload staging, cvt at frag-read -----
// z=0: Qb = q@wqT^T (scaled); z=1: Kb = k@wkT^T; z=2 swapped: VT = wvT@v^T.
// Flat 768-block grid, XCD-swizzled: f = bx%8 + 8*(by + 8*(bx/8 + 4*z)).
// f32 operand tile: [128 rows][128B], row-XOR swizzle (unit ^= row&7) done
// by pre-swizzling the GLOBAL source (gload_lds writes linearly). Weight
// tile: bf16 as before (ksrc/fsw swizzle).
__global__ __launch_bounds__(256) void gemm_qkv(const float* __restrict__ Xq,
                                                const float* __restrict__ Xk,
                                                const float* __restrict__ Xv,
                                                const u16* __restrict__ WT,
                                                u16* __restrict__ Qb,
                                                u16* __restrict__ Kb,
                                                u16* __restrict__ VTb) {
  __shared__ __align__(16) char lds[24576];
  char* f32t = lds;                       // 16 KB f32 operand tile
  char* wtile = lds + 16384;              // 8 KB bf16 weight tile

  // decode XCD-swizzled flat id
  const int f = blockIdx.x;
  const int bxm = f & 7, r1 = f >> 3;
  const int by = r1 & 7, r2 = r1 >> 3;
  const int bxd = r2 & 3, z = r2 >> 2;
  const int bx = bxm + 8 * bxd;            // 0..31

  const u16* Gbf;      // bf16 operand (gload_lds, bf16 tile)
  const float* Gf32;   // f32 operand (gload_lds raw, f32 tile)
  int row0, n0;
  if (z == 2) {
    Gbf = WT + 2097152;             // A = wvT [1024][1024]
    Gf32 = Xv;                      // B = value rows (seq)
    row0 = by * 128;                // 8 row-blocks over 1024
    n0 = bx * 128;                  // 32 col-blocks over 4096
  } else {
    Gf32 = z ? Xk : Xq;             // A = x rows (seq)
    Gbf = WT + (size_t)z * 1048576; // B = wT
    row0 = bx * 128;                // 32 row-blocks over 4096
    n0 = by * 128;                  // 8 col-blocks over 1024
  }
  const int frow0 = (z == 2) ? n0 : row0;   // f32 operand tile base row
  const int wrow0 = (z == 2) ? row0 : n0;   // weight operand tile base row

  const int tid = threadIdx.x;
  const int w = tid >> 6, lane = tid & 63;
  const int g = lane >> 4, c = lane & 15;
  const int wr = w >> 1, wc = w & 1;

  f32x4 acc[4][4];
#pragma unroll
  for (int i = 0; i < 4; ++i)
#pragma unroll
    for (int j = 0; j < 4; ++j) acc[i][j] = (f32x4){0.f, 0.f, 0.f, 0.f};

  const int sub = lane >> 2;                       // row within 16-row chunk
  const int kq = lane & 3;                         // k-group slot
  const int ksrc = (kq ^ ((sub >> 1) & 3)) * 8;    // swizzled source k-group
  const int fsw = ((c >> 1) & 3);                  // frag-read swizzle key

  // f32 staging: lane's dest slot is (row = j*32 + w*8 + lane>>3, unit = lane&7);
  // source col-group pre-swizzled so LDS holds unit u = cg ^ (row&7).
  const int fsrow = w * 8 + (lane >> 3);           // row within 32-row segment
  const int fscg = ((lane & 7) ^ (lane >> 3)) * 4; // source col-group elems

  for (int kt = 0; kt < 32; ++kt) {
    const int k0 = kt * 32;
    // ---- stage f32 operand raw: 4 fire-and-forget gloads
#pragma unroll
    for (int j = 0; j < 4; ++j)
      gload_lds16(Gf32 + (size_t)(frow0 + j * 32 + fsrow) * 1024 + k0 + fscg,
                  f32t + j * 4096 + w * 1024);
    // ---- stage bf16 weight operand: 2 fire-and-forget gloads
#pragma unroll
    for (int it = 0; it < 2; ++it) {
      const int ch = w * 2 + it;
      const int row = ch * 16 + sub;
      gload_lds16(Gbf + (size_t)(wrow0 + row) * 1024 + k0 + ksrc, wtile + ch * 1024);
    }
    __syncthreads();

    bf16x8 af[4], bfr[4];
    if (z != 2) {
      // A from f32 tile (cvt), B from bf16 weight tile
#pragma unroll
      for (int mi = 0; mi < 4; ++mi) {
        const int rr = wr * 64 + mi * 16 + c;
        const int rs = rr & 7;
        const f32x4 lo = *(const f32x4*)(f32t + rr * 128 + (((2 * g) ^ rs) << 4));
        const f32x4 hi = *(const f32x4*)(f32t + rr * 128 + (((2 * g + 1) ^ rs) << 4));
        s16x8 o;
        o[0] = (short)to_bf16(lo[0]); o[1] = (short)to_bf16(lo[1]);
        o[2] = (short)to_bf16(lo[2]); o[3] = (short)to_bf16(lo[3]);
        o[4] = (short)to_bf16(hi[0]); o[5] = (short)to_bf16(hi[1]);
        o[6] = (short)to_bf16(hi[2]); o[7] = (short)to_bf16(hi[3]);
        af[mi] = frag_cast(o);
      }
#pragma unroll
      for (int ni = 0; ni < 4; ++ni)
        bfr[ni] = frag_cast(*(const s16x8*)(wtile + (wc * 64 + ni * 16 + c) * 64 + ((g ^ fsw) << 4)));
    } else {
      // A from bf16 weight tile, B from f32 tile (cvt)
#pragma unroll
      for (int mi = 0; mi < 4; ++mi)
        af[mi] = frag_cast(*(const s16x8*)(wtile + (wr * 64 + mi * 16 + c) * 64 + ((g ^ fsw) << 4)));
#pragma unroll
      for (int ni = 0; ni < 4; ++ni) {
        const int rr = wc * 64 + ni * 16 + c;
        const int rs = rr & 7;
        const f32x4 lo = *(const f32x4*)(f32t + rr * 128 + (((2 * g) ^ rs) << 4));
        const f32x4 hi = *(const f32x4*)(f32t + rr * 128 + (((2 * g + 1) ^ rs) << 4));
        s16x8 o;
        o[0] = (short)to_bf16(lo[0]); o[1] = (short)to_bf16(lo[1]);
        o[2] = (short)to_bf16(lo[2]); o[3] = (short)to_bf16(lo[3]);
        o[4] = (short)to_bf16(hi[0]); o[5] = (short)to_bf16(hi[1]);
        o[6] = (short)to_bf16(hi[2]); o[7] = (short)to_bf16(hi[3]);
        bfr[ni] = frag_cast(o);
      }
    }
#pragma unroll
    for (int mi = 0; mi < 4; ++mi)
#pragma unroll
      for (int ni = 0; ni < 4; ++ni)
        acc[mi][ni] = mfma16(af[mi], bfr[ni], acc[mi][ni]);
    __syncthreads();
  }

  const float sc = (z == 0) ? QSC : 1.0f;
#pragma unroll
  for (int mi = 0; mi < 4; ++mi) {
    const int rowb = row0 + wr * 64 + mi * 16 + g * 4;
#pragma unroll
    for (int ni = 0; ni < 4; ++ni) {
      const int col = n0 + wc * 64 + ni * 16 + c;
#pragma unroll
      for (int r = 0; r < 4; ++r) {
        const int row = rowb + r;
        const float v = acc[mi][ni][r] * sc;
        if (z == 2) {
          // row = h*64+d, col = b*2048+s
          const int hh = row >> 6, d = row & 63;
          const int bb = col >> 11, s = col & 2047;
          VTb[((size_t)((bb * 16 + hh) * 64 + d)) * 2048 + s] = to_bf16(v);
        } else {
          u16* C = z == 0 ? Qb : Kb;
          C[(size_t)row * 1024 + col] = to_bf16(v);
        }
      }
    }
  }
}

// ---------------- out projection GEMM: BM=64, BN=128, f32 out ------------
// Flat 512-block grid, XCD-swizzled: f = bx%8 + 8*(by + 8*(bx/8)).
__global__ __launch_bounds__(256) void gemm_out(const u16* __restrict__ A,
                                                const u16* __restrict__ BT,
                                                float* __restrict__ C) {
  __shared__ u16 As[64 * 32];
  __shared__ u16 Bs[128 * 32];
  const int f = blockIdx.x;
  const int bxm = f & 7, r1 = f >> 3;
  const int by = r1 & 7, bxd = r1 >> 3;    // bxd 0..7
  const int bx = bxm + 8 * bxd;            // 0..63
  const int row0 = bx * 64;
  const int n0 = by * 128;

  const int tid = threadIdx.x;
  const int w = tid >> 6, lane = tid & 63;
  const int g = lane >> 4, c = lane & 15;
  const int wr = w >> 1, wc = w & 1;

  f32x4 acc[2][4];
#pragma unroll
  for (int i = 0; i < 2; ++i)
#pragma unroll
    for (int j = 0; j < 4; ++j) acc[i][j] = (f32x4){0.f, 0.f, 0.f, 0.f};

  const int sub = lane >> 2;
  const int kq = lane & 3;
  const int ksrc = (kq ^ ((sub >> 1) & 3)) * 8;
  const int fsw = ((c >> 1) & 3);

  for (int kt = 0; kt < 32; ++kt) {
    const int k0 = kt * 32;
    {
      const int row = w * 16 + sub;
      gload_lds16(A + (size_t)(row0 + row) * 1024 + k0 + ksrc, (char*)As + w * 1024);
    }
#pragma unroll
    for (int it = 0; it < 2; ++it) {
      const int ch = w * 2 + it;
      const int row = ch * 16 + sub;
      gload_lds16(BT + (size_t)(n0 + row) * 1024 + k0 + ksrc, (char*)Bs + ch * 1024);
    }
    __syncthreads();

    bf16x8 af[2], bfr[4];
#pragma unroll
    for (int mi = 0; mi < 2; ++mi)
      af[mi] = frag_cast(*(const s16x8*)((const char*)As + (wr * 32 + mi * 16 + c) * 64 + ((g ^ fsw) << 4)));
#pragma unroll
    for (int ni = 0; ni < 4; ++ni)
      bfr[ni] = frag_cast(*(const s16x8*)((const char*)Bs + (wc * 64 + ni * 16 + c) * 64 + ((g ^ fsw) << 4)));
#pragma unroll
    for (int mi = 0; mi < 2; ++mi)
#pragma unroll
      for (int ni = 0; ni < 4; ++ni)
        acc[mi][ni] = mfma16(af[mi], bfr[ni], acc[mi][ni]);
    __syncthreads();
  }

#pragma unroll
  for (int mi = 0; mi < 2; ++mi) {
    const int rowb = row0 + wr * 32 + mi * 16 + g * 4;
#pragma unroll
    for (int ni = 0; ni < 4; ++ni) {
      const int col = n0 + wc * 64 + ni * 16 + c;
#pragma unroll
      for (int r = 0; r < 4; ++r)
        C[(size_t)(rowb + r) * 1024 + col] = acc[mi][ni][r];
    }
  }
}

// ---------------- causal flash attention, 8-wave, KVBLK=128 ---------------
// grid (40, 32) remapped XCD-wise. Slice covers <=4 kv tile-pairs
// (ns=(x+4)>>2; 40 slices/bh). 8 waves x 16 q-rows. Permuted-K LDS slot
// (kv&0x63)|((kv&4)<<2)|((kv&0x18)>>1); QK^T C-slot (kvf,g,r) holds
// kv=32(kvf>>1)+4(kvf&1)+8g+r -> PV A-frags packed in place. l via
// ones-MFMA. Writes bf16 partial O + f32 (m,l).
__global__ __launch_bounds__(512, 4) void attn_fwd(const u16* __restrict__ Qb,
                                                   const u16* __restrict__ Kb,
                                                   const u16* __restrict__ VTb,
                                                   u16* __restrict__ PO,
                                                   float* __restrict__ ML) {
  __shared__ u16 Ks[2][128 * 64];   // [buf][slot][d] swizzled   (32 KB)
  __shared__ u16 VTs[2][64 * 128];  // [buf][d][kv] swizzled     (32 KB)

  const int tid = threadIdx.x;
  const int w = tid >> 6, lane = tid & 63;
  const int g = lane >> 4, c = lane & 15;

  // XCD-aware remap: flat -> logical so each XCD gets 4 consecutive bh
  const int flat = blockIdx.x + 40 * blockIdx.y;
  const int logical = (flat & 7) * 160 + (flat >> 3);
  const int slice_id = logical % 40;
  const int bh = logical / 40;
  const int b = bh >> 4, h = bh & 15;

  // decode slice id -> (q-block x, slice sid); ns(x) = (x+4)>>2 over pairs
  int sid = slice_id, x = 0;
  for (; x < 16; ++x) {
    const int ns_ = (x + 4) >> 2;
    if (sid < ns_) break;
    sid -= ns_;
  }
  const int ns = (x + 4) >> 2;
  const int np = x + 1;                       // kv tile-pairs for q-block x
  const int t0 = (sid * np) / ns, t1 = ((sid + 1) * np) / ns;
  const int sg = slice_id + 40 * bh;          // global slice id
  const int q0w = x * 128 + w * 16;           // this wave's first q row

  // Q fragments (B-operand: n=q, k=d) in registers
  bf16x8 qfr[2];
#pragma unroll
  for (int ch = 0; ch < 2; ++ch)
    qfr[ch] = frag_cast(*(const s16x8*)(Qb + (size_t)(b * SEQ + q0w + c) * 1024 + h * 64 + ch * 32 + g * 8));

  s16x8 ones_s;
#pragma unroll
  for (int j = 0; j < 8; ++j) ones_s[j] = (short)0x3F80;  // bf16 1.0
  const bf16x8 onesf = frag_cast(ones_s);

  f32x4 oacc[4];
#pragma unroll
  for (int j = 0; j < 4; ++j) oacc[j] = (f32x4){0.f, 0.f, 0.f, 0.f};
  f32x4 lacc = (f32x4){0.f, 0.f, 0.f, 0.f};
  float m_run = -1e30f;

  // staging geometry
  const int srow = tid >> 3;        // K: 0..63 (+64 on 2nd pass)
  const int scol = (tid & 7) * 8;   // K col elems
  const int vd = tid >> 4;          // V: 0..31 (+32 on 2nd pass)
  const int vcol = (tid & 15) * 8;  // V col elems (kv within pair)

  s16x8 kreg[2], vreg[2];
#define LOADKV(T)                                                                              \
  {                                                                                            \
    const int kv0_ = (T)*128;                                                                  \
    _Pragma("unroll") for (int it = 0; it < 2; ++it) {                                         \
      kreg[it] = *(const s16x8*)(Kb + (size_t)(b * SEQ + kv0_ + srow + it * 64) * 1024 +       \
                                 h * 64 + scol);                                               \
      vreg[it] = *(const s16x8*)(VTb + ((size_t)(bh * 64 + vd + it * 32)) * 2048 + kv0_ +      \
                                 vcol);                                                        \
    }                                                                                          \
  }
#define WRITEKV(BUF)                                                                           \
  {                                                                                            \
    _Pragma("unroll") for (int it = 0; it < 2; ++it) {                                         \
      const int rr_ = srow + it * 64;                                                          \
      const int pr_ = (rr_ & 0x63) | ((rr_ & 4) << 2) | ((rr_ & 0x18) >> 1);                   \
      *(s16x8*)((char*)Ks[BUF] + pr_ * 128 + ((scol * 2) ^ ((pr_ & 7) << 4))) = kreg[it];      \
      const int vr_ = vd + it * 32;                                                            \
      *(s16x8*)((char*)VTs[BUF] + vr_ * 256 + ((vcol * 2) ^ ((vr_ & 7) << 4))) = vreg[it];     \
    }                                                                                          \
  }

  LOADKV(t0);
  WRITEKV(0);
  __syncthreads();

  int cur = 0;
  for (int t = t0; t < t1; ++t) {
    const bool pre = (t + 1 < t1);
    if (pre) LOADKV(t + 1);          // issue early; lands during compute

    const int kv0 = t * 128;
    if (!(kv0 > q0w + 15)) {         // wave has live rows in this pair
      // ---- S^T = K * Q^T over 128 kv: 8 kvf frags
      f32x4 sa[8];
#pragma unroll
      for (int i = 0; i < 8; ++i) sa[i] = (f32x4){0.f, 0.f, 0.f, 0.f};
#pragma unroll
      for (int kvf = 0; kvf < 8; ++kvf) {
        const int kr = kvf * 16 + c;
        const int rb = kr * 128, swz = (kr & 7) << 4;
#pragma unroll
        for (int ch = 0; ch < 2; ++ch) {
          const bf16x8 ak = frag_cast(*(const s16x8*)((char*)Ks[cur] + rb + ((ch * 64 + g * 16) ^ swz)));
          sa[kvf] = mfma16(ak, qfr[ch], sa[kvf]);
        }
      }

      // ---- mask (diagonal pairs only) + tile max
      float mt = -1e30f;
      if (kv0 + 127 > q0w) {         // diagonal pair: mask with permuted kv
        const int q_abs = q0w + c;
#pragma unroll
        for (int kvf = 0; kvf < 8; ++kvf) {
          const int kvb = kv0 + (kvf >> 1) * 32 + (kvf & 1) * 4 + 8 * g;
#pragma unroll
          for (int r = 0; r < 4; ++r) {
            float s = sa[kvf][r];
            if (kvb + r > q_abs) s = -30000.f;
            sa[kvf][r] = s;
            mt = fmaxf(mt, s);
          }
        }
      } else {
#pragma unroll
        for (int kvf = 0; kvf < 8; ++kvf)
#pragma unroll
          for (int r = 0; r < 4; ++r) mt = fmaxf(mt, sa[kvf][r]);
      }
      mt = fmaxf(mt, __shfl_xor(mt, 16));
      mt = fmaxf(mt, __shfl_xor(mt, 32));

      if (__any(mt > m_run + 8.f)) {   // defer-max (T13)
        const float m_new = fmaxf(m_run, mt);
        const float alpha = __builtin_amdgcn_exp2f(m_run - m_new);
        m_run = m_new;
#pragma unroll
        for (int r = 0; r < 4; ++r) {
          const float ar = __shfl(alpha, g * 4 + r);
#pragma unroll
          for (int df = 0; df < 4; ++df) oacc[df][r] *= ar;
          lacc[r] *= ar;
        }
      }

      // ---- exp2 + pack in place into PV A-fragments (4 ch of 32 kv)
      s16x8 pk[4];
#pragma unroll
      for (int kvf = 0; kvf < 8; ++kvf)
#pragma unroll
        for (int r = 0; r < 4; ++r) {
          const float p = __builtin_amdgcn_exp2f(sa[kvf][r] - m_run);
          pk[kvf >> 1][(kvf & 1) * 4 + r] = (short)to_bf16(p);
        }

      // ---- O += P*V ; l += P*1 (row-sum via MFMA, no shfl)
#pragma unroll
      for (int ch = 0; ch < 4; ++ch) {
        const bf16x8 ap = frag_cast(pk[ch]);
#pragma unroll
        for (int df = 0; df < 4; ++df) {
          const int dr = df * 16 + c;
          const bf16x8 bv = frag_cast(*(const s16x8*)((char*)VTs[cur] + dr * 256 +
                                                      ((ch * 64 + g * 16) ^ ((dr & 7) << 4))));
          oacc[df] = mfma16(ap, bv, oacc[df]);
        }
        lacc = mfma16(ap, onesf, lacc);
      }
    }

    if (pre) WRITEKV(cur ^ 1);   // write next buffer (others still read cur)
    __syncthreads();
    cur ^= 1;
  }

  // epilogue: bf16 unnormalized partial O; f32 (m,l)
  const size_t pob = (size_t)sg * 8192;
#pragma unroll
  for (int r = 0; r < 4; ++r) {
    const int row = w * 16 + g * 4 + r;
#pragma unroll
    for (int df = 0; df < 4; ++df)
      PO[pob + row * 64 + df * 16 + c] = to_bf16(oacc[df][r]);
  }
  if (g == 0)
    ML[sg * 256 + (w * 16 + c) * 2 + 0] = m_run;     // m for q=c
  if (c == 0) {
#pragma unroll
    for (int r = 0; r < 4; ++r)
      ML[sg * 256 + (w * 16 + g * 4 + r) * 2 + 1] = lacc[r];  // l for q=4g+r
  }
}

// ---------------- merge split-kv partials -> bf16 Ob ----------------------
// grid (16, 32), 512 thr: x = q-block (128 rows), y = bh. row=tid/4, 16 cols.
__global__ __launch_bounds__(512) void attn_merge(const u16* __restrict__ PO,
                                                  const float* __restrict__ ML,
                                                  u16* __restrict__ Ob) {
  const int x = blockIdx.x, bh = blockIdx.y;
  const int b = bh >> 4, h = bh & 15;
  const int tid = threadIdx.x;
  const int row = tid >> 2, c0 = (tid & 3) << 4;

  int base = 0;
  for (int xp = 0; xp < x; ++xp) base += (xp + 4) >> 2;
  const int ns = (x + 4) >> 2;
  const int sg0 = base + 40 * bh;

  float m[4], l[4], a[4];
  float M = -3e38f;
  for (int i = 0; i < ns; ++i) {
    m[i] = ML[(sg0 + i) * 256 + row * 2 + 0];
    l[i] = ML[(sg0 + i) * 256 + row * 2 + 1];
    M = fmaxf(M, m[i]);
  }
  float denom = 0.f;
  for (int i = 0; i < ns; ++i) {
    a[i] = __builtin_amdgcn_exp2f(m[i] - M);
    denom += a[i] * l[i];
  }
  const float inv = 1.f / denom;

  float o[16];
#pragma unroll
  for (int j = 0; j < 16; ++j) o[j] = 0.f;
  for (int i = 0; i < ns; ++i) {
    const float s = a[i] * inv;
    const u16* p = PO + (size_t)(sg0 + i) * 8192 + row * 64 + c0;
    const s16x8 v0 = *(const s16x8*)p;
    const s16x8 v1 = *(const s16x8*)(p + 8);
#pragma unroll
    for (int j = 0; j < 8; ++j) {
      o[j] += s * from_bf16((u16)v0[j]);
      o[8 + j] += s * from_bf16((u16)v1[j]);
    }
  }

  s16x8 lo, hi;
#pragma unroll
  for (int j = 0; j < 8; ++j) {
    lo[j] = (short)to_bf16(o[j]);
    hi[j] = (short)to_bf16(o[8 + j]);
  }
  u16* dst = Ob + (size_t)(b * SEQ + x * 128 + row) * 1024 + h * 64 + c0;
  *(s16x8*)dst = lo;
  *(s16x8*)(dst + 8) = hi;
}

// --------------------------------------------------------------------------
extern "C" void kernel_launch(void* const* d_in, const int* in_sizes, int n_in,
                              void* d_out, int out_size, void* d_ws, size_t ws_size,
                              hipStream_t stream) {
  const float* query = (const float*)d_in[0];
  const float* key_ = (const float*)d_in[1];
  const float* value = (const float*)d_in[2];
  const float* w_q = (const float*)d_in[3];
  const float* w_k = (const float*)d_in[4];
  const float* w_v = (const float*)d_in[5];
  const float* w_o = (const float*)d_in[6];

  char* ws = (char*)d_ws;
  u16* PO = (u16*)(ws + 0);
  u16* wT = (u16*)(ws + 25165824);
  float* ML = (float*)(ws + 25165824);   // aliases wqT/wkT (dead post-qkv)
  u16* Qb = (u16*)(ws + 33554432);
  u16* Kb = (u16*)(ws + 41943040);
  u16* VTb = (u16*)(ws + 50331648);
  u16* Ob = (u16*)(ws + 58720256);

  transpose_w<<<dim3(32, 32, 4), dim3(32, 8), 0, stream>>>(w_q, w_k, w_v, w_o, wT);
  gemm_qkv<<<dim3(768), 256, 0, stream>>>(query, key_, value, wT, Qb, Kb, VTb);
  attn_fwd<<<dim3(40, 32), 512, 0, stream>>>(Qb, Kb, VTb, PO, ML);
  attn_merge<<<dim3(16, 32), 512, 0, stream>>>(PO, ML, Ob);
  gemm_out<<<dim3(512), 256, 0, stream>>>(Ob, wT + 3145728, (float*)d_out);
}